// Round 1
// baseline (165.432 us; speedup 1.0000x reference)
//
#include <hip/hip_runtime.h>

#define TW 32
#define TH 32
#define R  5
#define KW 11
#define W2 (TW + 2*R)   // 42
#define H2 (TH + 2*R)   // 42
#define IMG 512
#define NB (16*16*32)   // total blocks / partials

#define C1f 0.0001f     // 0.01^2
#define C2f 0.0009f     // 0.03^2

__device__ __forceinline__ void make_window(float* w) {
    float s = 0.f;
#pragma unroll
    for (int i = 0; i < KW; ++i) {
        float d = (float)(i - R);
        w[i] = expf(-(d * d) * (1.0f / (2.0f * 1.5f * 1.5f)));
        s += w[i];
    }
    float inv = 1.0f / s;
#pragma unroll
    for (int i = 0; i < KW; ++i) w[i] *= inv;
}

__global__ __launch_bounds__(256) void ssim_tile_kernel(
    const float* __restrict__ x, const float* __restrict__ y,
    float* __restrict__ partials)
{
    __shared__ float sx[H2][W2];
    __shared__ float sy[H2][W2];
    __shared__ float hb[5][H2][TW];  // horizontal-filtered: x, y, x2, y2, xy
    __shared__ float wsum_s[4];

    float w[KW];
    make_window(w);

    const int tc = blockIdx.x;   // tile col
    const int tr = blockIdx.y;   // tile row
    const int b  = blockIdx.z;   // batch
    const int tx = threadIdx.x;  // 0..31
    const int ty = threadIdx.y;  // 0..7
    const int tid = ty * 32 + tx;

    const size_t imgBase = (size_t)b * IMG * IMG;
    const int gc0 = tc * TW - R;
    const int gr0 = tr * TH - R;

    // ---- stage x,y tiles (with halo) into LDS, zero-padded at image edges
    float* sxf = &sx[0][0];
    float* syf = &sy[0][0];
    for (int i = tid; i < H2 * W2; i += 256) {
        int rr = i / W2, cc = i - rr * W2;
        int gr = gr0 + rr, gc = gc0 + cc;
        bool in = (gr >= 0) && (gr < IMG) && (gc >= 0) && (gc < IMG);
        size_t idx = imgBase + (size_t)gr * IMG + (size_t)gc;
        float xv = in ? x[idx] : 0.f;
        float yv = in ? y[idx] : 0.f;
        sxf[i] = xv;
        syf[i] = yv;
    }
    __syncthreads();

    // ---- horizontal 11-tap pass for all 5 quantities (shared LDS reads)
    for (int i = tid; i < H2 * TW; i += 256) {
        int rr = i >> 5, cc = i & 31;
        float a0 = 0.f, a1 = 0.f, a2 = 0.f, a3 = 0.f, a4 = 0.f;
#pragma unroll
        for (int j = 0; j < KW; ++j) {
            float px = sx[rr][cc + j];
            float py = sy[rr][cc + j];
            float wj = w[j];
            a0 += wj * px;
            a1 += wj * py;
            a2 += wj * (px * px);
            a3 += wj * (py * py);
            a4 += wj * (px * py);
        }
        hb[0][rr][cc] = a0;
        hb[1][rr][cc] = a1;
        hb[2][rr][cc] = a2;
        hb[3][rr][cc] = a3;
        hb[4][rr][cc] = a4;
    }
    __syncthreads();

    // ---- vertical 11-tap pass + SSIM epilogue; each thread does 4 rows
    float lsum = 0.f;
#pragma unroll
    for (int k = 0; k < 4; ++k) {
        int rr = ty + k * 8;  // output row within tile (0..31)
        float m0 = 0.f, m1 = 0.f, m2 = 0.f, m3 = 0.f, m4 = 0.f;
#pragma unroll
        for (int j = 0; j < KW; ++j) {
            float wj = w[j];
            m0 += wj * hb[0][rr + j][tx];
            m1 += wj * hb[1][rr + j][tx];
            m2 += wj * hb[2][rr + j][tx];
            m3 += wj * hb[3][rr + j][tx];
            m4 += wj * hb[4][rr + j][tx];
        }
        float mux = m0, muy = m1;
        float sxx = m2 - mux * mux;
        float syy = m3 - muy * muy;
        float sxy = m4 - mux * muy;
        float num = (2.f * mux * muy + C1f) * (2.f * sxy + C2f);
        float den = (mux * mux + muy * muy + C1f) * (sxx + syy + C2f);
        float ssim = num / (den + 1e-12f);
        ssim = fminf(fmaxf(ssim, -1.f + 1e-6f), 1.f - 1e-6f);
        lsum += ssim;
    }

    // ---- block reduction -> one partial per block (deterministic final pass)
#pragma unroll
    for (int off = 32; off > 0; off >>= 1)
        lsum += __shfl_down(lsum, off, 64);
    if ((tid & 63) == 0) wsum_s[tid >> 6] = lsum;
    __syncthreads();
    if (tid == 0) {
        float s = wsum_s[0] + wsum_s[1] + wsum_s[2] + wsum_s[3];
        partials[((size_t)blockIdx.z * gridDim.y + blockIdx.y) * gridDim.x + blockIdx.x] = s;
    }
}

__global__ __launch_bounds__(256) void ssim_finalize(
    const float* __restrict__ partials, float* __restrict__ out)
{
    __shared__ float wsum_s[4];
    float s = 0.f;
    for (int i = threadIdx.x; i < NB; i += 256) s += partials[i];
#pragma unroll
    for (int off = 32; off > 0; off >>= 1)
        s += __shfl_down(s, off, 64);
    if ((threadIdx.x & 63) == 0) wsum_s[threadIdx.x >> 6] = s;
    __syncthreads();
    if (threadIdx.x == 0) {
        float t = wsum_s[0] + wsum_s[1] + wsum_s[2] + wsum_s[3];
        out[0] = 1.0f - t / (float)(32 * 512 * 512);
    }
}

extern "C" void kernel_launch(void* const* d_in, const int* in_sizes, int n_in,
                              void* d_out, int out_size, void* d_ws, size_t ws_size,
                              hipStream_t stream) {
    const float* x = (const float*)d_in[0];
    const float* y = (const float*)d_in[1];
    float* out = (float*)d_out;
    float* partials = (float*)d_ws;  // NB floats; every slot written each launch

    dim3 grid(16, 16, 32);   // tile-col, tile-row, batch
    dim3 block(32, 8);
    ssim_tile_kernel<<<grid, block, 0, stream>>>(x, y, partials);
    ssim_finalize<<<1, 256, 0, stream>>>(partials, out);
}

// Round 2
// 131.895 us; speedup vs baseline: 1.2543x; 1.2543x over previous
//
#include <hip/hip_runtime.h>

#define IMG    512
#define TW     32
#define TH     64
#define R      5
#define KW     11
#define HB_H   (TH + 2*R)      // 74
#define HB_W   33              // 32 used + 1 float4 pad (bank de-alias)
#define GX     (IMG / TW)      // 16
#define GY     (IMG / TH)      // 8
#define NBATCH 32
#define NB     (GX * GY * NBATCH)  // 4096 partials

#define C1f 0.0001f            // 0.01^2
#define C2f 0.0009f            // 0.03^2

__device__ __forceinline__ void make_window(float* w) {
    float s = 0.f;
#pragma unroll
    for (int i = 0; i < KW; ++i) {
        float d = (float)(i - R);
        w[i] = expf(-(d * d) * (1.0f / (2.0f * 1.5f * 1.5f)));
        s += w[i];
    }
    float inv = 1.0f / s;
#pragma unroll
    for (int i = 0; i < KW; ++i) w[i] *= inv;
}

__global__ __launch_bounds__(256, 3) void ssim_tile_kernel(
    const float* __restrict__ x, const float* __restrict__ y,
    float* __restrict__ partials)
{
    __shared__ float4 hb4[HB_H][HB_W];  // (mu_x, mu_y, E[xx], E[yy]) horiz-filtered
    __shared__ float  hb1[HB_H][HB_W];  // E[xy] horiz-filtered
    __shared__ float  red[4];

    float w[KW];
    make_window(w);

    const int tc = blockIdx.x;   // tile col (32 wide)
    const int tr = blockIdx.y;   // tile row (64 tall)
    const int b  = blockIdx.z;
    const int tid = threadIdx.x; // 0..255

    const size_t imgBase = (size_t)b * IMG * IMG;
    const int gr0 = tr * TH - R;

    // ================= horizontal pass: global -> LDS =================
    // work item = (row rr of 74) x (group g of 8, each = 4 consecutive cols)
    for (int it = tid; it < HB_H * 8; it += 256) {
        const int rr = it >> 3;
        const int g  = it & 7;
        const int gr = gr0 + rr;
        const bool rowok = (gr >= 0) && (gr < IMG);
        const int grc = rowok ? gr : 0;
        const float4* rx = (const float4*)(x + imgBase + (size_t)grc * IMG);
        const float4* ry = (const float4*)(y + imgBase + (size_t)grc * IMG);

        // aligned float4 window: first float4 index; floats [base-8, base+12)
        // where base = tc*32 + 4g. Taps need floats base-5 .. base+8 = f[3..16].
        const int c4 = tc * 8 + g - 2;
        float fx[20], fy[20];
#pragma unroll
        for (int i = 0; i < 5; ++i) {
            int ci = c4 + i;
            bool ok = rowok && (ci >= 0) && (ci < IMG / 4);
            int cic = min(max(ci, 0), IMG / 4 - 1);
            float4 vx = rx[cic];
            float4 vy = ry[cic];
            float m = ok ? 1.f : 0.f;
            fx[4*i+0] = vx.x * m; fx[4*i+1] = vx.y * m;
            fx[4*i+2] = vx.z * m; fx[4*i+3] = vx.w * m;
            fy[4*i+0] = vy.x * m; fy[4*i+1] = vy.y * m;
            fy[4*i+2] = vy.z * m; fy[4*i+3] = vy.w * m;
        }
        // shared products for the 14 window floats
        float xx[14], yy[14], xy[14];
#pragma unroll
        for (int t = 0; t < 14; ++t) {
            float px = fx[3 + t], py = fy[3 + t];
            xx[t] = px * px; yy[t] = py * py; xy[t] = px * py;
        }
#pragma unroll
        for (int k = 0; k < 4; ++k) {
            float ax = 0.f, ay = 0.f, axx = 0.f, ayy = 0.f, axy = 0.f;
#pragma unroll
            for (int t = 0; t < KW; ++t) {
                float wt = w[t];
                int j = k + t;
                ax  += wt * fx[3 + j];
                ay  += wt * fy[3 + j];
                axx += wt * xx[j];
                ayy += wt * yy[j];
                axy += wt * xy[j];
            }
            hb4[rr][4*g + k] = make_float4(ax, ay, axx, ayy);
            hb1[rr][4*g + k] = axy;
        }
    }
    __syncthreads();

    // ================= vertical pass + SSIM epilogue =================
    const int tx = tid & 31;   // col in tile
    const int ty = tid >> 5;   // 0..7 -> rows [8*ty, 8*ty+8)
    const int r0 = ty * 8;

    float a0[8], a1[8], a2[8], a3[8], a4[8];
#pragma unroll
    for (int k = 0; k < 8; ++k) { a0[k]=0.f; a1[k]=0.f; a2[k]=0.f; a3[k]=0.f; a4[k]=0.f; }

#pragma unroll
    for (int t = 0; t < 18; ++t) {          // tap rows r0 .. r0+17
        float4 v4 = hb4[r0 + t][tx];
        float  v1 = hb1[r0 + t][tx];
#pragma unroll
        for (int k = 0; k < 8; ++k) {
            if (t - k >= 0 && t - k < KW) {  // constant-folds under full unroll
                float wt = w[t - k];
                a0[k] += wt * v4.x;
                a1[k] += wt * v4.y;
                a2[k] += wt * v4.z;
                a3[k] += wt * v4.w;
                a4[k] += wt * v1;
            }
        }
    }

    float lsum = 0.f;
#pragma unroll
    for (int k = 0; k < 8; ++k) {
        float mux = a0[k], muy = a1[k];
        float sxx = a2[k] - mux * mux;
        float syy = a3[k] - muy * muy;
        float sxy = a4[k] - mux * muy;
        float num = (2.f * mux * muy + C1f) * (2.f * sxy + C2f);
        float den = (mux * mux + muy * muy + C1f) * (sxx + syy + C2f);
        float ssim = num / (den + 1e-12f);
        ssim = fminf(fmaxf(ssim, -1.f + 1e-6f), 1.f - 1e-6f);
        lsum += ssim;
    }

    // ================= block reduction =================
#pragma unroll
    for (int off = 32; off > 0; off >>= 1)
        lsum += __shfl_down(lsum, off, 64);
    if ((tid & 63) == 0) red[tid >> 6] = lsum;
    __syncthreads();
    if (tid == 0) {
        float s = red[0] + red[1] + red[2] + red[3];
        partials[((size_t)b * GY + tr) * GX + tc] = s;
    }
}

__global__ __launch_bounds__(256) void ssim_finalize(
    const float* __restrict__ partials, float* __restrict__ out)
{
    __shared__ float red[4];
    float s = 0.f;
    for (int i = threadIdx.x; i < NB; i += 256) s += partials[i];
#pragma unroll
    for (int off = 32; off > 0; off >>= 1)
        s += __shfl_down(s, off, 64);
    if ((threadIdx.x & 63) == 0) red[threadIdx.x >> 6] = s;
    __syncthreads();
    if (threadIdx.x == 0) {
        float t = red[0] + red[1] + red[2] + red[3];
        out[0] = 1.0f - t / (float)(NBATCH * IMG * IMG);
    }
}

extern "C" void kernel_launch(void* const* d_in, const int* in_sizes, int n_in,
                              void* d_out, int out_size, void* d_ws, size_t ws_size,
                              hipStream_t stream) {
    const float* x = (const float*)d_in[0];
    const float* y = (const float*)d_in[1];
    float* out = (float*)d_out;
    float* partials = (float*)d_ws;  // NB floats; every slot written each launch

    dim3 grid(GX, GY, NBATCH);
    dim3 block(256);
    ssim_tile_kernel<<<grid, block, 0, stream>>>(x, y, partials);
    ssim_finalize<<<1, 256, 0, stream>>>(partials, out);
}